// Round 7
// baseline (513.903 us; speedup 1.0000x reference)
//
#include <hip/hip_runtime.h>

#define B_   64
#define T_   1024
#define C_   256
#define NEGF (-4294967295.0f)   // float(-2**32+1) == -2^32, matches reference fp32 cast
#define LN_EPS 1e-9f

typedef short  short8 __attribute__((ext_vector_type(8)));
typedef float  f32x4  __attribute__((ext_vector_type(4)));

union S8 { short8 v; unsigned int w[4]; };

// float -> bf16 (RNE), packed pair
__device__ __forceinline__ unsigned int pk2(float x, float y) {
  unsigned a = __float_as_uint(x); a = (a + 0x7fffu + ((a >> 16) & 1u)) >> 16;
  unsigned b = __float_as_uint(y); b = (b + 0x7fffu + ((b >> 16) & 1u)) >> 16;
  return a | (b << 16);
}

// async global->LDS, 16 B per lane
__device__ __forceinline__ void async16(const void* g, void* l) {
  __builtin_amdgcn_global_load_lds(
      (const __attribute__((address_space(1))) void*)g,
      (__attribute__((address_space(3))) void*)l,
      16, 0, 0);
}

// ---------------- small kernels ----------------

__global__ void detect_kernel(const unsigned int* __restrict__ mw,
                              int* __restrict__ flag) {
  int idx = blockIdx.x * 256 + threadIdx.x;   // 16384 words, safe for u8 or i32 buffer
  if (mw[idx] > 1u) atomicOr(flag, 1);
}

__global__ void finalize_kernel(const float* __restrict__ accum,
                                float* __restrict__ out) {
  int idx = blockIdx.x * 256 + threadIdx.x;   // B*C = 16384
  out[idx] = accum[idx] * (1.0f / T_);
}

// ---------------- pre-pass: bf16 K image + V^T image + colsum + sb ----------------
// One block per (b, 32-row tile); x read exactly once.
// K image: row-major [row][256], 16B slot ck stored at ck ^ (row&31).
// V^T image: [b][tile32][c][32 keys], 16B slot s stored at (s ^ ((c>>1)&3))&3.
// v2: K staged in LDS as bf16 (not fp32) -> phase 2 is a pure short repack;
// colsum partials computed in phase 1 from fp32 (exactness preserved).
__global__ __launch_bounds__(256) void convert_kv(const float* __restrict__ x,
                                                  const unsigned int* __restrict__ mw,
                                                  const int* __restrict__ flag,
                                                  short* __restrict__ xk,
                                                  short* __restrict__ xv,
                                                  float* __restrict__ colsum,
                                                  float2* __restrict__ sb) {
  __shared__ __align__(16) short Kb[32 * 256];   // 16 KB bf16 [k][slot^(k&7)]
  __shared__ __align__(16) short Vt[8192];       // 16 KB staged V^T tile
  __shared__ float csum[8][256];                 // 8 KB colsum partials
  const int blk = blockIdx.x, b = blk >> 5, tt = blk & 31;
  const int tid = threadIdx.x;
  const float* xt = x + (size_t)(b * 1024 + tt * 32) * 256;

  // sb entries for this block's 32 rows (score = s*scale + bias)
  if (tid < 32) {
    int idx = b * 1024 + tt * 32 + tid;
    int f = *flag;
    unsigned int w = mw[f ? (idx >> 2) : idx];
    unsigned int v = f ? ((w >> ((idx & 3) * 8)) & 0xffu) : w;
    sb[idx] = v ? make_float2(0.0625f, 0.f) : make_float2(0.f, NEGF);
  }

  // phase 1: coalesced row reads -> bf16 K-image (global+LDS) + colsum partials
  float myc[8];
#pragma unroll
  for (int e = 0; e < 8; ++e) myc[e] = 0.f;
  const int ck = tid & 31;         // fixed channel-chunk per thread across u
#pragma unroll
  for (int u = 0; u < 4; ++u) {
    int id = u * 256 + tid;        // 1024 items: 32 rows x 32 chunks
    int row = id >> 5;             // = u*8 + (tid>>5)
    const float* src = xt + row * 256 + ck * 8;
    float4 a  = *(const float4*)src;
    float4 c4 = *(const float4*)(src + 4);
    myc[0] += a.x;  myc[1] += a.y;  myc[2] += a.z;  myc[3] += a.w;
    myc[4] += c4.x; myc[5] += c4.y; myc[6] += c4.z; myc[7] += c4.w;
    S8 s; s.w[0] = pk2(a.x, a.y);  s.w[1] = pk2(a.z, a.w);
          s.w[2] = pk2(c4.x, c4.y); s.w[3] = pk2(c4.z, c4.w);
    *(short8*)(xk + (size_t)(b * 1024 + tt * 32 + row) * 256 + ((ck ^ row) << 3)) = s.v;
    *(short8*)&Kb[row * 256 + ((ck ^ (row & 7)) << 3)] = s.v;
  }
  {
    const int rg = tid >> 5;       // 0..7: thread's rows were {8u+rg}
#pragma unroll
    for (int e = 0; e < 8; ++e) csum[rg][ck * 8 + e] = myc[e];
  }
  __syncthreads();

  // phase 2: short repack Kb -> staged swizzled V^T tile (no reconversion)
  const int ck2 = tid >> 6, clo = tid & 63;
#pragma unroll
  for (int g = 0; g < 4; ++g) {
    int c = g * 64 + clo;
    unsigned short sv[8];
#pragma unroll
    for (int e = 0; e < 8; ++e) {
      int k = ck2 * 8 + e;
      sv[e] = (unsigned short)Kb[k * 256 + (((c >> 3) ^ (k & 7)) << 3) + (c & 7)];
    }
    S8 o;
    o.w[0] = (unsigned)sv[0] | ((unsigned)sv[1] << 16);
    o.w[1] = (unsigned)sv[2] | ((unsigned)sv[3] << 16);
    o.w[2] = (unsigned)sv[4] | ((unsigned)sv[5] << 16);
    o.w[3] = (unsigned)sv[6] | ((unsigned)sv[7] << 16);
    *(short8*)&Vt[c * 32 + (((ck2 ^ ((c >> 1) & 3)) & 3) << 3)] = o.v;
  }
  __syncthreads();

  // phase 3: linear coalesced copy-out of V^T tile + colsum reduce
  {
    float4* vo = (float4*)(xv + (size_t)(b * 32 + tt) * 8192);
    const float4* vi = (const float4*)Vt;
#pragma unroll
    for (int r = 0; r < 4; ++r) vo[r * 256 + tid] = vi[r * 256 + tid];
    float s = csum[0][tid] + csum[1][tid] + csum[2][tid] + csum[3][tid]
            + csum[4][tid] + csum[5][tid] + csum[6][tid] + csum[7][tid];
    atomicAdd(&colsum[b * 256 + tid], s);
  }
}

// ---------------- flash finalize helper ----------------
__device__ __forceinline__ void finalize_tile(
    f32x4* Oa, float m, float l, int b, int quad, int r,
    const float* __restrict__ colsum, const float* __restrict__ gamma,
    const float* __restrict__ beta, float* __restrict__ accum)
{
  float mr[4], li[4];
#pragma unroll
  for (int reg = 0; reg < 4; ++reg) {
    mr[reg] = __shfl(m, quad * 4 + reg, 64);
    float lr = __shfl(l, quad * 4 + reg, 64);
    li[reg] = 1.f / lr;
  }
#pragma unroll
  for (int ct = 0; ct < 16; ++ct) {
    float cs = colsum[b * C_ + ct * 16 + r] * (1.0f / T_);
#pragma unroll
    for (int reg = 0; reg < 4; ++reg)
      Oa[ct][reg] = (mr[reg] < -1.0e9f) ? cs : Oa[ct][reg] * li[reg];
  }
  float ts[16];
#pragma unroll
  for (int ct = 0; ct < 16; ++ct) ts[ct] = 0.f;
#pragma unroll
  for (int reg = 0; reg < 4; ++reg) {
    float s2 = 0.f;
#pragma unroll
    for (int ct = 0; ct < 16; ++ct) s2 += Oa[ct][reg];
    s2 += __shfl_xor(s2, 1, 64); s2 += __shfl_xor(s2, 2, 64);
    s2 += __shfl_xor(s2, 4, 64); s2 += __shfl_xor(s2, 8, 64);
    float mu = s2 * (1.0f / C_);
    float sq = 0.f;
#pragma unroll
    for (int ct = 0; ct < 16; ++ct) { float d = Oa[ct][reg] - mu; sq += d * d; }
    sq += __shfl_xor(sq, 1, 64); sq += __shfl_xor(sq, 2, 64);
    sq += __shfl_xor(sq, 4, 64); sq += __shfl_xor(sq, 8, 64);
    float rstd = rsqrtf(sq * (1.0f / C_) + LN_EPS);
#pragma unroll
    for (int ct = 0; ct < 16; ++ct) {
      int c = ct * 16 + r;
      ts[ct] += gamma[c] * (Oa[ct][reg] - mu) * rstd + beta[c];
    }
  }
#pragma unroll
  for (int ct = 0; ct < 16; ++ct) {
    ts[ct] += __shfl_xor(ts[ct], 16, 64);
    ts[ct] += __shfl_xor(ts[ct], 32, 64);
  }
  if (quad == 0) {
#pragma unroll
    for (int ct = 0; ct < 16; ++ct)
      atomicAdd(&accum[b * C_ + ct * 16 + r], ts[ct]);
  }
}

// ---------------- flash kernel ----------------
// 512 blocks of 512 threads (8 waves), 2 blocks/CU (64 KB LDS each),
// 16 waves/CU = 4/SIMD — double flash5's occupancy to hide ds_read latency.
// Block = (batch b, 128-row q-tile t); dispatch-order mapping pairs (b,t)
// and (b,7-t) on the same CU for balance (heuristic only). 32-key tiles,
// nt = 4(t+1), ascending; per-wave causal skip; one barrier per tile;
// double-buffered async DMA (32 KB/tile). Wave owns 16 q rows.
// T13 defer-max (THR=8). VGPR pinned <=128 via __launch_bounds__(512,4).
__global__ __launch_bounds__(512, 4) void flash9(
    const short* __restrict__ xk,
    const short* __restrict__ xv,
    const float2* __restrict__ sb,
    const float* __restrict__ gamma,
    const float* __restrict__ beta,
    const float* __restrict__ colsum,
    float* __restrict__ accum)
{
  __shared__ __align__(16) short KsD[2][32 * 256];   // 2 x 16 KB  K rows
  __shared__ __align__(16) short VtD[2][8192];       // 2 x 16 KB  V^T [c][32k]

  const int i0  = blockIdx.x;
  const int x8  = i0 & 7;           // XCD id (heuristic: round-robin dispatch)
  const int s   = i0 >> 3;          // 0..63
  const int sec = s >> 5;           // 0: first resident block on CU, 1: second
  const int j   = s & 31;
  const int b   = x8 + 8 * (j >> 2);          // batches = x8 (mod 8) on XCD x8
  const int t4  = j & 3;
  const int t   = sec ? (7 - t4) : t4;        // CU pair gets (t, 7-t), same b

  const int tid  = threadIdx.x;
  const int w    = tid >> 6;        // 0..7
  const int lane = tid & 63;
  const int quad = lane >> 4;
  const int r    = lane & 15;

  const int n0   = t * 128 + w * 16;
  const int qrow = n0 + r;
  const int nt   = 4 * (t + 1);     // 32-key tiles for this q-tile

  short8 qf[8];
  {
    const short* qp = xk + (size_t)(b * 1024 + qrow) * 256;
#pragma unroll
    for (int ks = 0; ks < 8; ++ks)
      qf[ks] = *(const short8*)(qp + (((ks * 4 + quad) ^ (qrow & 31)) << 3));
  }
  f32x4 Oa[16];
#pragma unroll
  for (int ct = 0; ct < 16; ++ct) Oa[ct] = (f32x4){0.f, 0.f, 0.f, 0.f};
  float m = NEGF, l = 0.f;

  // prefetch tile 0 into buf 0 (32-key tile: 16 KB K + 16 KB V, linear DMA)
  {
    const short* gk = xk + (size_t)(b * 1024) * 256;
    const short* gv = xv + (size_t)(b * 32) * 8192;
#pragma unroll
    for (int u = 0; u < 2; ++u) {
      int seg = w * 2 + u;          // 0..15, 1 KB each
      async16(gk + seg * 512 + lane * 8, &KsD[0][seg * 512]);
      async16(gv + seg * 512 + lane * 8, &VtD[0][seg * 512]);
    }
  }
  __syncthreads();

  for (int kt = 0; kt < nt; ++kt) {
    const int ibuf = kt & 1;
    if (kt + 1 < nt) {   // async prefetch next tile into other buffer
      const short* gk = xk + (size_t)(b * 1024 + (kt + 1) * 32) * 256;
      const short* gv = xv + (size_t)(b * 32 + kt + 1) * 8192;
#pragma unroll
      for (int u = 0; u < 2; ++u) {
        int seg = w * 2 + u;
        async16(gk + seg * 512 + lane * 8, &KsD[1 - ibuf][seg * 512]);
        async16(gv + seg * 512 + lane * 8, &VtD[1 - ibuf][seg * 512]);
      }
    }

    const int ktb = kt * 32;
    if (ktb <= n0 + 15) {   // wave-uniform causal tile skip
      // ---- scores S^T = K·Q^T  (32 keys = 2 m-tiles)
      float sc[8];
#pragma unroll
      for (int mt = 0; mt < 2; ++mt) {
        f32x4 acc = (f32x4){0.f, 0.f, 0.f, 0.f};
        const int row = mt * 16 + r;
#pragma unroll
        for (int ks = 0; ks < 8; ++ks) {
          short8 af = *(short8*)&KsD[ibuf][row * 256 + (((ks * 4 + quad) ^ (row & 31)) << 3)];
          acc = __builtin_amdgcn_mfma_f32_16x16x32_bf16(af, qf[ks], acc, 0, 0, 0);
        }
        const int j0 = ktb + mt * 16 + quad * 4;
        float4 sA = *(const float4*)(sb + (size_t)b * 1024 + j0);     // s0,b0,s1,b1
        float4 sB = *(const float4*)(sb + (size_t)b * 1024 + j0 + 2); // s2,b2,s3,b3
        sc[mt * 4 + 0] = acc[0] * sA.x + sA.y;
        sc[mt * 4 + 1] = acc[1] * sA.z + sA.w;
        sc[mt * 4 + 2] = acc[2] * sB.x + sB.y;
        sc[mt * 4 + 3] = acc[3] * sB.z + sB.w;
      }
      if (ktb + 31 > n0) {   // diagonal tiles: elementwise causal mask
#pragma unroll
        for (int k2 = 0; k2 < 8; ++k2) {
          int j2 = ktb + (k2 >> 2) * 16 + quad * 4 + (k2 & 3);
          if (j2 > qrow) sc[k2] = NEGF;
        }
      }

      // ---- online softmax (stats per q at lane&15, replicated via xor16/32)
      float mx = sc[0];
#pragma unroll
      for (int k2 = 1; k2 < 8; ++k2) mx = fmaxf(mx, sc[k2]);
      mx = fmaxf(mx, __shfl_xor(mx, 16, 64));
      mx = fmaxf(mx, __shfl_xor(mx, 32, 64));
      if (__ballot(mx > m + 8.f)) {   // T13 defer-max: rescale only on real growth
        const float mnew  = fmaxf(m, mx);
        const float alpha = __expf(m - mnew);   // NEGF-NEGF=0 -> 1; NEGF-real -> 0
        float ar[4];
#pragma unroll
        for (int reg = 0; reg < 4; ++reg) ar[reg] = __shfl(alpha, quad * 4 + reg, 64);
#pragma unroll
        for (int ct = 0; ct < 16; ++ct) {
          Oa[ct][0] *= ar[0]; Oa[ct][1] *= ar[1];
          Oa[ct][2] *= ar[2]; Oa[ct][3] *= ar[3];
        }
        l *= alpha;
        m = mnew;
      }
      float p[8], ps = 0.f;
#pragma unroll
      for (int k2 = 0; k2 < 8; ++k2) { p[k2] = __expf(sc[k2] - m); ps += p[k2]; }
      ps += __shfl_xor(ps, 16, 64);
      ps += __shfl_xor(ps, 32, 64);
      l += ps;

      // ---- P (C-layout) -> one PV A-frag via 8 shuffles
      S8 pf;
      {
        unsigned q0 = pk2(p[0], p[1]);
        unsigned q1 = pk2(p[2], p[3]);
        unsigned q2 = pk2(p[4], p[5]);
        unsigned q3 = pk2(p[6], p[7]);
        int s0l = ((quad & 1) << 5) + r, s1l = s0l + 16;
        unsigned u0 = __shfl((int)q0, s0l, 64), u1 = __shfl((int)q1, s0l, 64);
        unsigned u2 = __shfl((int)q2, s0l, 64), u3 = __shfl((int)q3, s0l, 64);
        unsigned v0 = __shfl((int)q0, s1l, 64), v1 = __shfl((int)q1, s1l, 64);
        unsigned v2 = __shfl((int)q2, s1l, 64), v3 = __shfl((int)q3, s1l, 64);
        bool hi = quad >= 2;
        pf.w[0] = hi ? u2 : u0; pf.w[1] = hi ? u3 : u1;
        pf.w[2] = hi ? v2 : v0; pf.w[3] = hi ? v3 : v1;
      }

      // ---- PV: O[q][c] += P[q][j] V[j][c]  (one 32-key tile)
#pragma unroll
      for (int ct = 0; ct < 16; ++ct) {
        int c = ct * 16 + r;
        int cs_off = c * 32 + (((quad ^ ((c >> 1) & 3)) & 3) << 3);
        short8 b0 = *(short8*)&VtD[ibuf][cs_off];
        Oa[ct] = __builtin_amdgcn_mfma_f32_16x16x32_bf16(pf.v, b0, Oa[ct], 0, 0, 0);
      }
    }

    __syncthreads();   // drains prefetched tile(kt+1) (issued a full tile ago)
  } // kt

  finalize_tile(Oa, m, l, b, quad, r, colsum, gamma, beta, accum);
}

// ---------------- launch ----------------

extern "C" void kernel_launch(void* const* d_in, const int* in_sizes, int n_in,
                              void* d_out, int out_size, void* d_ws, size_t ws_size,
                              hipStream_t stream) {
  const float* x     = (const float*)d_in[0];
  const void*  km    = d_in[1];
  const float* gamma = (const float*)d_in[2];
  const float* beta  = (const float*)d_in[3];
  float* out = (float*)d_out;

  // ws layout
  const size_t off_sb = 131200;                       // float2[B*T] = 512 KB
  const size_t off_xk = 655616;                       // 32 MB bf16 K-image
  const size_t off_xv = off_xk + 33554432;            // 32 MB bf16 V^T-image

  float*  accum  = (float*)d_ws;
  float*  colsum = (float*)((char*)d_ws + 65536);
  int*    flag   = (int*)((char*)d_ws + 131072);
  float2* sb     = (float2*)((char*)d_ws + off_sb);
  short*  xk     = (short*)((char*)d_ws + off_xk);
  short*  xv     = (short*)((char*)d_ws + off_xv);

  hipMemsetAsync(d_ws, 0, 131136, stream);   // accum + colsum + flag
  detect_kernel<<<64, 256, 0, stream>>>((const unsigned int*)km, flag);
  convert_kv<<<B_ * 32, 256, 0, stream>>>(x, (const unsigned int*)km, flag,
                                          xk, xv, colsum, sb);
  flash9<<<512, 512, 0, stream>>>(xk, xv, sb, gamma, beta, colsum, accum);
  finalize_kernel<<<B_ * C_ / 256, 256, 0, stream>>>(accum, out);
}

// Round 8
// 172.269 us; speedup vs baseline: 2.9831x; 2.9831x over previous
//
#include <hip/hip_runtime.h>

#define B_   64
#define T_   1024
#define C_   256
#define NEGF (-4294967295.0f)   // float(-2**32+1) == -2^32, matches reference fp32 cast
#define LN_EPS 1e-9f

typedef short  short8 __attribute__((ext_vector_type(8)));
typedef float  f32x4  __attribute__((ext_vector_type(4)));

union S8 { short8 v; unsigned int w[4]; };

// float -> bf16 (RNE), packed pair
__device__ __forceinline__ unsigned int pk2(float x, float y) {
  unsigned a = __float_as_uint(x); a = (a + 0x7fffu + ((a >> 16) & 1u)) >> 16;
  unsigned b = __float_as_uint(y); b = (b + 0x7fffu + ((b >> 16) & 1u)) >> 16;
  return a | (b << 16);
}

// async global->LDS, 16 B per lane
__device__ __forceinline__ void async16(const void* g, void* l) {
  __builtin_amdgcn_global_load_lds(
      (const __attribute__((address_space(1))) void*)g,
      (__attribute__((address_space(3))) void*)l,
      16, 0, 0);
}

// ---------------- small kernels ----------------

__global__ void detect_kernel(const unsigned int* __restrict__ mw,
                              int* __restrict__ flag) {
  int idx = blockIdx.x * 256 + threadIdx.x;   // 16384 words, safe for u8 or i32 buffer
  if (mw[idx] > 1u) atomicOr(flag, 1);
}

// ---------------- pre-pass: bf16 K image + V^T image + colsum + sb ----------------
// One block per (b, 32-row tile); x read exactly once.
// K image: row-major [row][256], 16B slot ck stored at ck ^ (row&31).
// V^T image: [b][tile32][c][32 keys], 16B slot s stored at (s ^ ((c>>1)&3))&3.
// K staged in LDS as bf16 -> phase 2 is a pure short repack; colsum partials
// computed in phase 1 from fp32 (exactness preserved).
__global__ __launch_bounds__(256) void convert_kv(const float* __restrict__ x,
                                                  const unsigned int* __restrict__ mw,
                                                  const int* __restrict__ flag,
                                                  short* __restrict__ xk,
                                                  short* __restrict__ xv,
                                                  float* __restrict__ colsum,
                                                  float2* __restrict__ sb) {
  __shared__ __align__(16) short Kb[32 * 256];   // 16 KB bf16 [k][slot^(k&7)]
  __shared__ __align__(16) short Vt[8192];       // 16 KB staged V^T tile
  __shared__ float csum[8][256];                 // 8 KB colsum partials
  const int blk = blockIdx.x, b = blk >> 5, tt = blk & 31;
  const int tid = threadIdx.x;
  const float* xt = x + (size_t)(b * 1024 + tt * 32) * 256;

  // sb entries for this block's 32 rows (score = s*scale + bias)
  if (tid < 32) {
    int idx = b * 1024 + tt * 32 + tid;
    int f = *flag;
    unsigned int w = mw[f ? (idx >> 2) : idx];
    unsigned int v = f ? ((w >> ((idx & 3) * 8)) & 0xffu) : w;
    sb[idx] = v ? make_float2(0.0625f, 0.f) : make_float2(0.f, NEGF);
  }

  // phase 1: coalesced row reads -> bf16 K-image (global+LDS) + colsum partials
  float myc[8];
#pragma unroll
  for (int e = 0; e < 8; ++e) myc[e] = 0.f;
  const int ck = tid & 31;         // fixed channel-chunk per thread across u
#pragma unroll
  for (int u = 0; u < 4; ++u) {
    int id = u * 256 + tid;        // 1024 items: 32 rows x 32 chunks
    int row = id >> 5;             // = u*8 + (tid>>5)
    const float* src = xt + row * 256 + ck * 8;
    float4 a  = *(const float4*)src;
    float4 c4 = *(const float4*)(src + 4);
    myc[0] += a.x;  myc[1] += a.y;  myc[2] += a.z;  myc[3] += a.w;
    myc[4] += c4.x; myc[5] += c4.y; myc[6] += c4.z; myc[7] += c4.w;
    S8 s; s.w[0] = pk2(a.x, a.y);  s.w[1] = pk2(a.z, a.w);
          s.w[2] = pk2(c4.x, c4.y); s.w[3] = pk2(c4.z, c4.w);
    *(short8*)(xk + (size_t)(b * 1024 + tt * 32 + row) * 256 + ((ck ^ row) << 3)) = s.v;
    *(short8*)&Kb[row * 256 + ((ck ^ (row & 7)) << 3)] = s.v;
  }
  {
    const int rg = tid >> 5;       // 0..7: thread's rows were {8u+rg}
#pragma unroll
    for (int e = 0; e < 8; ++e) csum[rg][ck * 8 + e] = myc[e];
  }
  __syncthreads();

  // phase 2: short repack Kb -> staged swizzled V^T tile (no reconversion)
  const int ck2 = tid >> 6, clo = tid & 63;
#pragma unroll
  for (int g = 0; g < 4; ++g) {
    int c = g * 64 + clo;
    unsigned short sv[8];
#pragma unroll
    for (int e = 0; e < 8; ++e) {
      int k = ck2 * 8 + e;
      sv[e] = (unsigned short)Kb[k * 256 + (((c >> 3) ^ (k & 7)) << 3) + (c & 7)];
    }
    S8 o;
    o.w[0] = (unsigned)sv[0] | ((unsigned)sv[1] << 16);
    o.w[1] = (unsigned)sv[2] | ((unsigned)sv[3] << 16);
    o.w[2] = (unsigned)sv[4] | ((unsigned)sv[5] << 16);
    o.w[3] = (unsigned)sv[6] | ((unsigned)sv[7] << 16);
    *(short8*)&Vt[c * 32 + (((ck2 ^ ((c >> 1) & 3)) & 3) << 3)] = o.v;
  }
  __syncthreads();

  // phase 3: linear coalesced copy-out of V^T tile + colsum reduce
  {
    float4* vo = (float4*)(xv + (size_t)(b * 32 + tt) * 8192);
    const float4* vi = (const float4*)Vt;
#pragma unroll
    for (int r = 0; r < 4; ++r) vo[r * 256 + tid] = vi[r * 256 + tid];
    float s = csum[0][tid] + csum[1][tid] + csum[2][tid] + csum[3][tid]
            + csum[4][tid] + csum[5][tid] + csum[6][tid] + csum[7][tid];
    atomicAdd(&colsum[b * 256 + tid], s);
  }
}

// ---------------- flash finalize helper ----------------
// Writes this wave's 16-q-row contribution, pre-scaled by 1/T, directly into
// the output (mean over time) — finalize_kernel eliminated.
__device__ __forceinline__ void finalize_tile(
    f32x4* Oa, float m, float l, int b, int quad, int r,
    const float* __restrict__ colsum, const float* __restrict__ gamma,
    const float* __restrict__ beta, float* __restrict__ out)
{
  float mr[4], li[4];
#pragma unroll
  for (int reg = 0; reg < 4; ++reg) {
    mr[reg] = __shfl(m, quad * 4 + reg, 64);
    float lr = __shfl(l, quad * 4 + reg, 64);
    li[reg] = 1.f / lr;
  }
#pragma unroll
  for (int ct = 0; ct < 16; ++ct) {
    float cs = colsum[b * C_ + ct * 16 + r] * (1.0f / T_);
#pragma unroll
    for (int reg = 0; reg < 4; ++reg)
      Oa[ct][reg] = (mr[reg] < -1.0e9f) ? cs : Oa[ct][reg] * li[reg];
  }
  float ts[16];
#pragma unroll
  for (int ct = 0; ct < 16; ++ct) ts[ct] = 0.f;
#pragma unroll
  for (int reg = 0; reg < 4; ++reg) {
    float s2 = 0.f;
#pragma unroll
    for (int ct = 0; ct < 16; ++ct) s2 += Oa[ct][reg];
    s2 += __shfl_xor(s2, 1, 64); s2 += __shfl_xor(s2, 2, 64);
    s2 += __shfl_xor(s2, 4, 64); s2 += __shfl_xor(s2, 8, 64);
    float mu = s2 * (1.0f / C_);
    float sq = 0.f;
#pragma unroll
    for (int ct = 0; ct < 16; ++ct) { float d = Oa[ct][reg] - mu; sq += d * d; }
    sq += __shfl_xor(sq, 1, 64); sq += __shfl_xor(sq, 2, 64);
    sq += __shfl_xor(sq, 4, 64); sq += __shfl_xor(sq, 8, 64);
    float rstd = rsqrtf(sq * (1.0f / C_) + LN_EPS);
#pragma unroll
    for (int ct = 0; ct < 16; ++ct) {
      int c = ct * 16 + r;
      ts[ct] += gamma[c] * (Oa[ct][reg] - mu) * rstd + beta[c];
    }
  }
#pragma unroll
  for (int ct = 0; ct < 16; ++ct) {
    ts[ct] += __shfl_xor(ts[ct], 16, 64);
    ts[ct] += __shfl_xor(ts[ct], 32, 64);
  }
  if (quad == 0) {
#pragma unroll
    for (int ct = 0; ct < 16; ++ct)
      atomicAdd(&out[b * C_ + ct * 16 + r], ts[ct] * (1.0f / T_));
  }
}

// ---------------- flash kernel ----------------
// 256 blocks of 512 threads (8 waves), 1 block/CU, 128 KB LDS.
// Block = (batch b, 128-row q-tile pair (t, 7-t)); UNIFORM 18 iterations of
// 64-key tiles: ascending 0..2(t+1)-1 for qt=t, then descending 15-2t..0 for
// qt=7-t (kt = idx < h0len ? idx : 17-idx). All blocks of a batch touch <=2
// tile streams at any instant; XCD clustering (blockIdx&7 hosts batches = x
// mod 8) keeps those streams L2-resident. Wave owns 16 q rows. Double-
// buffered async DMA staging (64 KB/tile), ONE barrier per 64-key tile.
// T13 defer-max (THR=8). T5 setprio(1) around both MFMA clusters.
// NOTE (r7 lesson): this structure needs ~140 regs -> 2 waves/SIMD max;
// __launch_bounds__(512,2). Do NOT push occupancy via launch bounds (r7:
// (512,4) -> 64 VGPR cap -> 1.4 GB scratch spill, 410 us).
__global__ __launch_bounds__(512, 2) void flash5(
    const short* __restrict__ xk,
    const short* __restrict__ xv,
    const float2* __restrict__ sb,
    const float* __restrict__ gamma,
    const float* __restrict__ beta,
    const float* __restrict__ colsum,
    float* __restrict__ out)
{
  __shared__ __align__(16) short KsD[2][64 * 256];       // 2 x 32 KB  K rows
  __shared__ __align__(16) short VtD[2][2 * 256 * 32];   // 2 x 32 KB  V^T halves

  const int i0 = blockIdx.x;
  const int x8 = i0 & 7;            // XCD id (heuristic: round-robin dispatch)
  const int s  = i0 >> 3;           // 0..31
  const int b  = x8 + 8 * (s & 7);  // batches = x8 (mod 8) cluster on XCD x8
  const int t  = s >> 3;            // 0..3 -> q-tile pair (t, 7-t)

  const int tid  = threadIdx.x;
  const int w    = tid >> 6;        // 0..7
  const int lane = tid & 63;
  const int quad = lane >> 4;
  const int r    = lane & 15;

  const int h0len = 2 * (t + 1);    // ascending tiles for qt=t

  // ---- state for current q-tile
  int qt   = t;
  int n0   = qt * 128 + w * 16;
  int qrow = n0 + r;
  short8 qf[8];
  {
    const short* qp = xk + (size_t)(b * 1024 + qrow) * 256;
#pragma unroll
    for (int ks = 0; ks < 8; ++ks)
      qf[ks] = *(const short8*)(qp + (((ks * 4 + quad) ^ (qrow & 31)) << 3));
  }
  f32x4 Oa[16];
#pragma unroll
  for (int ct = 0; ct < 16; ++ct) Oa[ct] = (f32x4){0.f, 0.f, 0.f, 0.f};
  float m = NEGF, l = 0.f;

  // prefetch tile 0 into buf 0 (64-key tile: 32 KB K + 32 KB V, linear DMA)
  {
    const short* gk = xk + (size_t)(b * 1024) * 256;
    const short* gv = xv + (size_t)(b * 32) * 8192;
#pragma unroll
    for (int u = 0; u < 4; ++u) {
      int seg = w * 4 + u;          // 0..31, 1 KB each
      async16(gk + seg * 512 + lane * 8, &KsD[0][seg * 512]);
      async16(gv + seg * 512 + lane * 8, &VtD[0][seg * 512]);
    }
  }
  __syncthreads();

  for (int idx = 0; idx < 18; ++idx) {
    const int ibuf = idx & 1;
    if (idx < 17) {   // async prefetch tile(idx+1) into other buffer
      const int nt2 = (idx + 1 < h0len) ? (idx + 1) : (17 - (idx + 1));
      const short* gk = xk + (size_t)(b * 1024 + nt2 * 64) * 256;
      const short* gv = xv + (size_t)(b * 32 + nt2 * 2) * 8192;
#pragma unroll
      for (int u = 0; u < 4; ++u) {
        int seg = w * 4 + u;
        async16(gk + seg * 512 + lane * 8, &KsD[1 - ibuf][seg * 512]);
        async16(gv + seg * 512 + lane * 8, &VtD[1 - ibuf][seg * 512]);
      }
    }

    const int kt  = (idx < h0len) ? idx : (17 - idx);
    const int ktb = kt * 64;
    if (ktb <= n0 + 15) {   // wave-uniform causal tile skip
      // ---- scores S^T = K·Q^T  (64 keys = 4 m-tiles)
      float sc[16];
      __builtin_amdgcn_s_setprio(1);
#pragma unroll
      for (int mt = 0; mt < 4; ++mt) {
        f32x4 acc = (f32x4){0.f, 0.f, 0.f, 0.f};
        const int row = mt * 16 + r;
#pragma unroll
        for (int ks = 0; ks < 8; ++ks) {
          short8 af = *(short8*)&KsD[ibuf][row * 256 + (((ks * 4 + quad) ^ (row & 31)) << 3)];
          acc = __builtin_amdgcn_mfma_f32_16x16x32_bf16(af, qf[ks], acc, 0, 0, 0);
        }
        const int j0 = ktb + mt * 16 + quad * 4;
        float4 sA = *(const float4*)(sb + (size_t)b * 1024 + j0);     // s0,b0,s1,b1
        float4 sB = *(const float4*)(sb + (size_t)b * 1024 + j0 + 2); // s2,b2,s3,b3
        sc[mt * 4 + 0] = acc[0] * sA.x + sA.y;
        sc[mt * 4 + 1] = acc[1] * sA.z + sA.w;
        sc[mt * 4 + 2] = acc[2] * sB.x + sB.y;
        sc[mt * 4 + 3] = acc[3] * sB.z + sB.w;
      }
      __builtin_amdgcn_s_setprio(0);
      if (ktb + 63 > n0) {   // diagonal tiles: elementwise causal mask
#pragma unroll
        for (int k2 = 0; k2 < 16; ++k2) {
          int j = ktb + (k2 >> 2) * 16 + quad * 4 + (k2 & 3);
          if (j > qrow) sc[k2] = NEGF;
        }
      }

      // ---- online softmax (stats per q at lane&15, replicated via xor16/32)
      float mx = sc[0];
#pragma unroll
      for (int k2 = 1; k2 < 16; ++k2) mx = fmaxf(mx, sc[k2]);
      mx = fmaxf(mx, __shfl_xor(mx, 16, 64));
      mx = fmaxf(mx, __shfl_xor(mx, 32, 64));
      if (__ballot(mx > m + 8.f)) {   // T13 defer-max: rescale only on real growth
        const float mnew  = fmaxf(m, mx);
        const float alpha = __expf(m - mnew);   // NEGF-NEGF=0 -> 1; NEGF-real -> 0
        float ar[4];
#pragma unroll
        for (int reg = 0; reg < 4; ++reg) ar[reg] = __shfl(alpha, quad * 4 + reg, 64);
#pragma unroll
        for (int ct = 0; ct < 16; ++ct) {
          Oa[ct][0] *= ar[0]; Oa[ct][1] *= ar[1];
          Oa[ct][2] *= ar[2]; Oa[ct][3] *= ar[3];
        }
        l *= alpha;
        m = mnew;
      }
      float p[16], ps = 0.f;
#pragma unroll
      for (int k2 = 0; k2 < 16; ++k2) { p[k2] = __expf(sc[k2] - m); ps += p[k2]; }
      ps += __shfl_xor(ps, 16, 64);
      ps += __shfl_xor(ps, 32, 64);
      l += ps;

      // ---- P (C-layout) -> two PV A-frags via 8 shuffles each
      S8 pf[2];
#pragma unroll
      for (int hh = 0; hh < 2; ++hh) {
        unsigned q0 = pk2(p[hh * 8 + 0], p[hh * 8 + 1]);
        unsigned q1 = pk2(p[hh * 8 + 2], p[hh * 8 + 3]);
        unsigned q2 = pk2(p[hh * 8 + 4], p[hh * 8 + 5]);
        unsigned q3 = pk2(p[hh * 8 + 6], p[hh * 8 + 7]);
        int s0l = ((quad & 1) << 5) + r, s1l = s0l + 16;
        unsigned u0 = __shfl((int)q0, s0l, 64), u1 = __shfl((int)q1, s0l, 64);
        unsigned u2 = __shfl((int)q2, s0l, 64), u3 = __shfl((int)q3, s0l, 64);
        unsigned v0 = __shfl((int)q0, s1l, 64), v1 = __shfl((int)q1, s1l, 64);
        unsigned v2 = __shfl((int)q2, s1l, 64), v3 = __shfl((int)q3, s1l, 64);
        bool hi = quad >= 2;
        pf[hh].w[0] = hi ? u2 : u0; pf[hh].w[1] = hi ? u3 : u1;
        pf[hh].w[2] = hi ? v2 : v0; pf[hh].w[3] = hi ? v3 : v1;
      }

      // ---- PV: O[q][c] += P[q][j] V[j][c]  (two 32-key halves)
      __builtin_amdgcn_s_setprio(1);
#pragma unroll
      for (int ct = 0; ct < 16; ++ct) {
        int c = ct * 16 + r;
        int cs_off = c * 32 + (((quad ^ ((c >> 1) & 3)) & 3) << 3);
        short8 b0 = *(short8*)&VtD[ibuf][cs_off];
        short8 b1 = *(short8*)&VtD[ibuf][8192 + cs_off];
        Oa[ct] = __builtin_amdgcn_mfma_f32_16x16x32_bf16(pf[0].v, b0, Oa[ct], 0, 0, 0);
        Oa[ct] = __builtin_amdgcn_mfma_f32_16x16x32_bf16(pf[1].v, b1, Oa[ct], 0, 0, 0);
      }
      __builtin_amdgcn_s_setprio(0);
    }

    // ---- boundary: finalize qt=t, reset state for qt=7-t (no LDS touched)
    if (idx == h0len - 1) {
      finalize_tile(Oa, m, l, b, quad, r, colsum, gamma, beta, out);
      qt = 7 - t;
      n0 = qt * 128 + w * 16;
      qrow = n0 + r;
      const short* qp = xk + (size_t)(b * 1024 + qrow) * 256;
#pragma unroll
      for (int ks = 0; ks < 8; ++ks)
        qf[ks] = *(const short8*)(qp + (((ks * 4 + quad) ^ (qrow & 31)) << 3));
#pragma unroll
      for (int ct = 0; ct < 16; ++ct) Oa[ct] = (f32x4){0.f, 0.f, 0.f, 0.f};
      m = NEGF; l = 0.f;
    }

    __syncthreads();   // drains prefetched tile(idx+1) (issued a full tile ago)
  } // idx

  // ---- finalize second q-tile (qt = 7-t)
  finalize_tile(Oa, m, l, b, quad, r, colsum, gamma, beta, out);
}

// ---------------- launch ----------------

extern "C" void kernel_launch(void* const* d_in, const int* in_sizes, int n_in,
                              void* d_out, int out_size, void* d_ws, size_t ws_size,
                              hipStream_t stream) {
  const float* x     = (const float*)d_in[0];
  const void*  km    = d_in[1];
  const float* gamma = (const float*)d_in[2];
  const float* beta  = (const float*)d_in[3];
  float* out = (float*)d_out;

  // ws layout
  const size_t off_sb = 131200;                       // float2[B*T] = 512 KB
  const size_t off_xk = 655616;                       // 32 MB bf16 K-image
  const size_t off_xv = off_xk + 33554432;            // 32 MB bf16 V^T-image

  float*  colsum = (float*)((char*)d_ws + 65536);
  int*    flag   = (int*)((char*)d_ws + 131072);
  float2* sb     = (float2*)((char*)d_ws + off_sb);
  short*  xk     = (short*)((char*)d_ws + off_xk);
  short*  xv     = (short*)((char*)d_ws + off_xv);

  hipMemsetAsync(d_ws, 0, 131136, stream);    // colsum + flag (accum slot unused)
  hipMemsetAsync(d_out, 0, out_size, stream); // flash atomically accumulates here
  detect_kernel<<<64, 256, 0, stream>>>((const unsigned int*)km, flag);
  convert_kv<<<B_ * 32, 256, 0, stream>>>(x, (const unsigned int*)km, flag,
                                          xk, xv, colsum, sb);
  flash5<<<256, 512, 0, stream>>>(xk, xv, sb, gamma, beta, colsum, out);
}